// Round 7
// baseline (5362.806 us; speedup 1.0000x reference)
//
#include <hip/hip_runtime.h>

#define T_SEQ 2048
#define NMORPH 6144
#define EMB 100
#define HID 128
#define GATES 512
#define LDA0 304
#define XPD 1024
#define TAGS 50

__device__ __forceinline__ float sigm(float x) {
  return 1.0f / (1.0f + __expf(-x));
}
__device__ __forceinline__ float tanh_f(float x) {
  x = fminf(fmaxf(x, -9.0f), 9.0f);
  float e2 = __expf(2.0f * x);
  return (e2 - 1.0f) / (e2 + 1.0f);
}

// ---------------- kernel 1: segment-sum of morpheme embeddings into inp[:,0:100]
__global__ void k_toksum(const float* __restrict__ W_wv,
                         const int* __restrict__ morp_ids,
                         const int* __restrict__ seg,
                         float* __restrict__ inp) {
  const int t = blockIdx.x;
  const int d = threadIdx.x;  // 0..127
  int a = 0, b = NMORPH;
  while (a < b) { int m = (a + b) >> 1; if (seg[m] < t) a = m + 1; else b = m; }
  const int lo = a;
  b = NMORPH;
  while (a < b) { int m = (a + b) >> 1; if (seg[m] <= t) a = m + 1; else b = m; }
  const int hi = a;
  if (d < EMB) {
    float s = 0.0f;
    for (int m = lo; m < hi; ++m)
      s += W_wv[(size_t)morp_ids[m] * EMB + d];
    inp[(size_t)t * LDA0 + d] = s;
  }
}

// ---------------- kernel 2: fill inp cols 100..303 (pred vec, dp emb, feat, pad)
__global__ void k_fill(const float* __restrict__ dp_table,
                       const int* __restrict__ dp_in,
                       const float* __restrict__ feat,
                       const int* __restrict__ pred_idx,
                       float* __restrict__ inp) {
  const int t = blockIdx.x;
  const int c = threadIdx.x;  // 0..255 -> col 100+c
  if (c >= 204) return;
  const int col = 100 + c;
  float v;
  if (col < 200)      v = inp[(size_t)pred_idx[0] * LDA0 + (col - 100)];
  else if (col < 264) v = dp_table[dp_in[t] * 64 + (col - 200)];
  else if (col < 300) v = feat[t * 36 + (col - 264)];
  else                v = 0.0f;  // pad cols 300..303
  inp[(size_t)t * LDA0 + col] = v;
}

// ---------------- kernel 3: xp[M x 1024] = A[M x K] @ [Wf;Wb]^T + [bf;bb]
__global__ __launch_bounds__(256) void k_gemm(
    const float* __restrict__ A, int lda, int K,
    const float* __restrict__ Wf, const float* __restrict__ Wb,
    const float* __restrict__ bf, const float* __restrict__ bb,
    float* __restrict__ out) {
  constexpr int BK = 16, LDT = 68;
  __shared__ float As[BK][LDT];
  __shared__ float Bs[BK][LDT];
  const int tid = threadIdx.x;
  const int tx = tid & 15, ty = tid >> 4;
  const int bm = blockIdx.x * 64;
  const int n0 = blockIdx.y * 64;
  const float* __restrict__ W  = (n0 < GATES) ? Wf : Wb;
  const float* __restrict__ bs = (n0 < GATES) ? bf : bb;
  const int nw = (n0 < GATES) ? n0 : n0 - GATES;
  const int ar = tid >> 2;
  const int ak = (tid & 3) * 4;
  float acc[4][4] = {};
  const int ktiles = (K + BK - 1) / BK;
  for (int kt = 0; kt < ktiles; ++kt) {
    const int k0 = kt * BK;
    float4 av = *(const float4*)&A[(size_t)(bm + ar) * lda + k0 + ak];
    float4 bv = make_float4(0.f, 0.f, 0.f, 0.f);
    if (k0 + ak < K)
      bv = *(const float4*)&W[(size_t)(nw + ar) * K + k0 + ak];
    __syncthreads();
    As[ak + 0][ar] = av.x; As[ak + 1][ar] = av.y;
    As[ak + 2][ar] = av.z; As[ak + 3][ar] = av.w;
    Bs[ak + 0][ar] = bv.x; Bs[ak + 1][ar] = bv.y;
    Bs[ak + 2][ar] = bv.z; Bs[ak + 3][ar] = bv.w;
    __syncthreads();
#pragma unroll
    for (int kk = 0; kk < BK; ++kk) {
      float4 a4 = *(const float4*)&As[kk][ty * 4];
      float4 b4 = *(const float4*)&Bs[kk][tx * 4];
      float a_[4] = {a4.x, a4.y, a4.z, a4.w};
      float b_[4] = {b4.x, b4.y, b4.z, b4.w};
#pragma unroll
      for (int i = 0; i < 4; ++i)
#pragma unroll
        for (int j = 0; j < 4; ++j)
          acc[i][j] = fmaf(a_[i], b_[j], acc[i][j]);
    }
  }
  const float4 bias4 = *(const float4*)&bs[nw + tx * 4];
#pragma unroll
  for (int i = 0; i < 4; ++i) {
    float4 o;
    o.x = acc[i][0] + bias4.x;
    o.y = acc[i][1] + bias4.y;
    o.z = acc[i][2] + bias4.z;
    o.w = acc[i][3] + bias4.w;
    *(float4*)&out[(size_t)(bm + ty * 4 + i) * XPD + n0 + tx * 4] = o;
  }
}

// ---------------- kernel 4: persistent LSTM recurrence, one block per direction
// ROUND 7 STRUCTURE: 1024 threads (16 waves, 4/SIMD, exactly 1 block/CU).
// A gate row is split across a LANE PAIR: thread = (row r = tid>>1,
// half = tid&1), each holding 64 weights (16 float4 = 64 VGPRs). Total
// per-thread register demand ~100 < the 128-VGPR cap of a 16-wave block, so
// the allocator has no reason to spill (rounds 1-6: 128-reg/thread demand was
// always spilled). Partial dots combine via __shfl_xor(.,1); h broadcast via
// uniform LDS reads (2 addresses/instr = free); xp staged through
// double-buffered LDS (issue loads at group start, write at group end).
__global__ __launch_bounds__(1024)
__attribute__((amdgpu_waves_per_eu(4, 4))) void k_lstm(
    const float* __restrict__ xp,     // [T][1024] (f cols 0:512, b cols 512:1024)
    const float* __restrict__ whh_f,  // [512][128]
    const float* __restrict__ whh_b,
    float* __restrict__ hout) {       // [T][256] (f cols 0:128, b cols 128:256)
  const int dir = blockIdx.x;
  const int tid = threadIdx.x;   // 0..1023
  const int r = tid >> 1;        // gate row 0..511
  const int half = tid & 1;      // which 64-wide half of the row
  const float* __restrict__ whh = dir ? whh_b : whh_f;
  const int xofs = dir * GATES;
  const int hofs = dir * HID;

  __shared__ __align__(16) float lh[HID];
  __shared__ __align__(16) float lg[GATES];
  __shared__ __align__(16) float lx[2 * 8 * GATES];  // 32 KB, dbuf x 8 steps

  // persistent weights: 64 per thread (half a gate row)
  float4 w4[16];
  {
    const float4* wrow = (const float4*)(whh + (size_t)r * HID + half * 64);
#pragma unroll
    for (int q = 0; q < 16; ++q) w4[q] = wrow[q];
  }

  // stage group 0 of xp into lx buffer 0 (thread covers 4 floats)
  const int xu = tid >> 7;             // step-in-group 0..7
  const int xc = (tid & 127) * 4;      // col 0..508
  {
    const int tt = dir ? (T_SEQ - 1 - xu) : xu;
    float4 xr = *(const float4*)&xp[(size_t)tt * XPD + xofs + xc];
    *(float4*)&lx[tid * 4] = xr;
  }

  float c = 0.0f;
  if (tid < HID) lh[tid] = 0.0f;
  __syncthreads();

  int buf = 0;
  for (int t0 = 0; t0 < T_SEQ; t0 += 8) {
    // issue next group's loads now (consumed at u==7); latency hides under 8 steps
    const int tb = (t0 + 8 < T_SEQ) ? t0 + 8 : 0;
    float4 xr;
    {
      const int t = tb + xu;
      const int tt = dir ? (T_SEQ - 1 - t) : t;
      xr = *(const float4*)&xp[(size_t)tt * XPD + xofs + xc];
    }
    const float* lxb = lx + buf * (8 * GATES);
#pragma unroll
    for (int u = 0; u < 8; ++u) {
      const int t = t0 + u;
      const int tt = dir ? (T_SEQ - 1 - t) : t;
      // half-row dot: 16 broadcast ds_read_b128 + 64 FMA (4 chains)
      const float4* lh4 = (const float4*)(lh + half * 64);
      float a0 = 0.f, a1 = 0.f, a2 = 0.f, a3 = 0.f;
#pragma unroll
      for (int q = 0; q < 16; ++q) {
        float4 hv = lh4[q];
        a0 = fmaf(w4[q].x, hv.x, a0);
        a1 = fmaf(w4[q].y, hv.y, a1);
        a2 = fmaf(w4[q].z, hv.z, a2);
        a3 = fmaf(w4[q].w, hv.w, a3);
      }
      float s = (a0 + a1) + (a2 + a3);
      s += __shfl_xor(s, 1);           // combine pair halves (in-wave)
      float g = s + lxb[u * GATES + r];
      // gate nonlinearity (wave-uniform: rows grouped 32/wave)
      float gn = (r < 2 * HID) ? sigm(g) : (r < 3 * HID) ? tanh_f(g) : sigm(g);
      if (!half) lg[r] = gn;
      asm volatile("s_waitcnt lgkmcnt(0)" ::: "memory");
      __builtin_amdgcn_s_barrier();
      if (tid < HID) {
        float gi = lg[tid];
        float gf = lg[HID + tid];
        float gg = lg[2 * HID + tid];
        float go = lg[3 * HID + tid];
        c = gf * c + gi * gg;
        float h = go * tanh_f(c);
        lh[tid] = h;
        hout[(size_t)tt * 256 + hofs + tid] = h;  // fire-and-forget store
      }
      if (u == 7) {
        // write next group's xp into the other buffer (loads issued 8 steps ago)
        asm volatile("s_waitcnt vmcnt(0)" ::: "memory");
        *(float4*)&lx[(buf ^ 1) * (8 * GATES) + tid * 4] = xr;
      }
      asm volatile("s_waitcnt lgkmcnt(0)" ::: "memory");
      __builtin_amdgcn_s_barrier();
    }
    buf ^= 1;
  }
}

// ---------------- kernel 5: tag_space = h2 @ W_out^T + b_out
__global__ void k_out(const float* __restrict__ h2,
                      const float* __restrict__ Wout,
                      const float* __restrict__ bout,
                      float* __restrict__ out) {
  __shared__ __align__(16) float hrow[256];
  const int t = blockIdx.x;
  const int tid = threadIdx.x;  // 64
  *(float4*)&hrow[tid * 4] = *(const float4*)&h2[(size_t)t * 256 + tid * 4];
  __syncthreads();
  if (tid < TAGS) {
    float acc = bout[tid];
    const float* w = &Wout[(size_t)tid * 256];
#pragma unroll 8
    for (int k = 0; k < 256; k += 4) {
      float4 wv = *(const float4*)&w[k];
      acc += hrow[k] * wv.x + hrow[k + 1] * wv.y + hrow[k + 2] * wv.z +
             hrow[k + 3] * wv.w;
    }
    out[(size_t)t * TAGS + tid] = acc;
  }
}

extern "C" void kernel_launch(void* const* d_in, const int* in_sizes, int n_in,
                              void* d_out, int out_size, void* d_ws, size_t ws_size,
                              hipStream_t stream) {
  const int*   morp_ids = (const int*)d_in[0];
  const int*   seg      = (const int*)d_in[1];
  const int*   pred_idx = (const int*)d_in[2];
  const int*   dp_in    = (const int*)d_in[3];
  const float* feat     = (const float*)d_in[4];
  const float* W_wv     = (const float*)d_in[5];
  const float* dp_table = (const float*)d_in[6];
  const float* W_out    = (const float*)d_in[7];
  const float* b_out    = (const float*)d_in[8];
  const float* w_ih_l0f = (const float*)d_in[9];
  const float* w_hh_l0f = (const float*)d_in[10];
  const float* b_l0f    = (const float*)d_in[11];
  const float* w_ih_l0b = (const float*)d_in[12];
  const float* w_hh_l0b = (const float*)d_in[13];
  const float* b_l0b    = (const float*)d_in[14];
  const float* w_ih_l1f = (const float*)d_in[15];
  const float* w_hh_l1f = (const float*)d_in[16];
  const float* b_l1f    = (const float*)d_in[17];
  const float* w_ih_l1b = (const float*)d_in[18];
  const float* w_hh_l1b = (const float*)d_in[19];
  const float* b_l1b    = (const float*)d_in[20];
  float* out = (float*)d_out;

  float* ws  = (float*)d_ws;
  float* inp = ws;                      // 2048*304
  float* xp  = inp + 2048 * LDA0;       // 2048*1024 (reused for both layers)
  float* h1  = xp + 2048 * XPD;         // 2048*256
  float* h2  = h1 + 2048 * 256;         // 2048*256

  k_toksum<<<2048, 128, 0, stream>>>(W_wv, morp_ids, seg, inp);
  k_fill<<<2048, 256, 0, stream>>>(dp_table, dp_in, feat, pred_idx, inp);

  dim3 gg(32, 16);
  k_gemm<<<gg, 256, 0, stream>>>(inp, LDA0, 300, w_ih_l0f, w_ih_l0b, b_l0f, b_l0b, xp);
  k_lstm<<<2, 1024, 0, stream>>>(xp, w_hh_l0f, w_hh_l0b, h1);
  k_gemm<<<gg, 256, 0, stream>>>(h1, 256, 256, w_ih_l1f, w_ih_l1b, b_l1f, b_l1b, xp);
  k_lstm<<<2, 1024, 0, stream>>>(xp, w_hh_l1f, w_hh_l1b, h2);
  k_out<<<2048, 64, 0, stream>>>(h2, W_out, b_out, out);
}

// Round 9
// 4037.383 us; speedup vs baseline: 1.3283x; 1.3283x over previous
//
#include <hip/hip_runtime.h>

#define T_SEQ 2048
#define NMORPH 6144
#define EMB 100
#define HID 128
#define GATES 512
#define LDA0 304
#define XPD 1024
#define TAGS 50

typedef float  fx4 __attribute__((ext_vector_type(4)));
typedef unsigned int ux4 __attribute__((ext_vector_type(4)));

__device__ __forceinline__ float sigm(float x) {
  return 1.0f / (1.0f + __expf(-x));
}
__device__ __forceinline__ float tanh_f(float x) {
  x = fminf(fmaxf(x, -9.0f), 9.0f);
  float e2 = __expf(2.0f * x);
  return (e2 - 1.0f) / (e2 + 1.0f);
}
// round-to-nearest-even fp32 -> bf16 (as uint), and back
__device__ __forceinline__ unsigned int f2bf1(float x) {
  unsigned int u = __float_as_uint(x);
  return (u + 0x7FFFu + ((u >> 16) & 1u)) >> 16;
}
__device__ __forceinline__ float bf2f(unsigned int h) {
  return __uint_as_float(h << 16);
}
__device__ __forceinline__ unsigned int pack2(float a, float b) {
  return f2bf1(a) | (f2bf1(b) << 16);
}
__device__ __forceinline__ float lof(float x) {
  return x - bf2f(f2bf1(x));
}

// ---------------- kernel 1: segment-sum of morpheme embeddings into inp[:,0:100]
__global__ void k_toksum(const float* __restrict__ W_wv,
                         const int* __restrict__ morp_ids,
                         const int* __restrict__ seg,
                         float* __restrict__ inp) {
  const int t = blockIdx.x;
  const int d = threadIdx.x;  // 0..127
  int a = 0, b = NMORPH;
  while (a < b) { int m = (a + b) >> 1; if (seg[m] < t) a = m + 1; else b = m; }
  const int lo = a;
  b = NMORPH;
  while (a < b) { int m = (a + b) >> 1; if (seg[m] <= t) a = m + 1; else b = m; }
  const int hi = a;
  if (d < EMB) {
    float s = 0.0f;
    for (int m = lo; m < hi; ++m)
      s += W_wv[(size_t)morp_ids[m] * EMB + d];
    inp[(size_t)t * LDA0 + d] = s;
  }
}

// ---------------- kernel 2: fill inp cols 100..303 (pred vec, dp emb, feat, pad)
__global__ void k_fill(const float* __restrict__ dp_table,
                       const int* __restrict__ dp_in,
                       const float* __restrict__ feat,
                       const int* __restrict__ pred_idx,
                       float* __restrict__ inp) {
  const int t = blockIdx.x;
  const int c = threadIdx.x;  // 0..255 -> col 100+c
  if (c >= 204) return;
  const int col = 100 + c;
  float v;
  if (col < 200)      v = inp[(size_t)pred_idx[0] * LDA0 + (col - 100)];
  else if (col < 264) v = dp_table[dp_in[t] * 64 + (col - 200)];
  else if (col < 300) v = feat[t * 36 + (col - 264)];
  else                v = 0.0f;  // pad cols 300..303
  inp[(size_t)t * LDA0 + col] = v;
}

// ---------------- kernel 3: xp[M x 1024] = A[M x K] @ [Wf;Wb]^T + [bf;bb]
__global__ __launch_bounds__(256) void k_gemm(
    const float* __restrict__ A, int lda, int K,
    const float* __restrict__ Wf, const float* __restrict__ Wb,
    const float* __restrict__ bf, const float* __restrict__ bb,
    float* __restrict__ out) {
  constexpr int BK = 16, LDT = 68;
  __shared__ float As[BK][LDT];
  __shared__ float Bs[BK][LDT];
  const int tid = threadIdx.x;
  const int tx = tid & 15, ty = tid >> 4;
  const int bm = blockIdx.x * 64;
  const int n0 = blockIdx.y * 64;
  const float* __restrict__ W  = (n0 < GATES) ? Wf : Wb;
  const float* __restrict__ bs = (n0 < GATES) ? bf : bb;
  const int nw = (n0 < GATES) ? n0 : n0 - GATES;
  const int ar = tid >> 2;
  const int ak = (tid & 3) * 4;
  float acc[4][4] = {};
  const int ktiles = (K + BK - 1) / BK;
  for (int kt = 0; kt < ktiles; ++kt) {
    const int k0 = kt * BK;
    float4 av = *(const float4*)&A[(size_t)(bm + ar) * lda + k0 + ak];
    float4 bv = make_float4(0.f, 0.f, 0.f, 0.f);
    if (k0 + ak < K)
      bv = *(const float4*)&W[(size_t)(nw + ar) * K + k0 + ak];
    __syncthreads();
    As[ak + 0][ar] = av.x; As[ak + 1][ar] = av.y;
    As[ak + 2][ar] = av.z; As[ak + 3][ar] = av.w;
    Bs[ak + 0][ar] = bv.x; Bs[ak + 1][ar] = bv.y;
    Bs[ak + 2][ar] = bv.z; Bs[ak + 3][ar] = bv.w;
    __syncthreads();
#pragma unroll
    for (int kk = 0; kk < BK; ++kk) {
      float4 a4 = *(const float4*)&As[kk][ty * 4];
      float4 b4 = *(const float4*)&Bs[kk][tx * 4];
      float a_[4] = {a4.x, a4.y, a4.z, a4.w};
      float b_[4] = {b4.x, b4.y, b4.z, b4.w};
#pragma unroll
      for (int i = 0; i < 4; ++i)
#pragma unroll
        for (int j = 0; j < 4; ++j)
          acc[i][j] = fmaf(a_[i], b_[j], acc[i][j]);
    }
  }
  const float4 bias4 = *(const float4*)&bs[nw + tx * 4];
#pragma unroll
  for (int i = 0; i < 4; ++i) {
    float4 o;
    o.x = acc[i][0] + bias4.x;
    o.y = acc[i][1] + bias4.y;
    o.z = acc[i][2] + bias4.z;
    o.w = acc[i][3] + bias4.w;
    *(float4*)&out[(size_t)(bm + ty * 4 + i) * XPD + n0 + tx * 4] = o;
  }
}

// Stash one packed bf16x8 fragment (4 dwords) into hard-named AGPRs.
#define STASH4(A0, A1, A2, A3, V)                                  \
  asm volatile("v_accvgpr_write_b32 " A0 ", %0\n\t"                \
               "v_accvgpr_write_b32 " A1 ", %1\n\t"                \
               "v_accvgpr_write_b32 " A2 ", %2\n\t"                \
               "v_accvgpr_write_b32 " A3 ", %3"                    \
               :: "v"(V[0]), "v"(V[1]), "v"(V[2]), "v"(V[3])       \
               : A0, A1, A2, A3)

// Load 8 fp32 weights, split into bf16 hi/lo, pack, stash hi+lo fragments.
#define FRAG(TN, KC, H0,H1,H2,H3, L0,L1,L2,L3)                     \
  do {                                                             \
    const float* wp_ = whh + (size_t)(wbase + (TN)*16 + ln15)*HID  \
                       + (KC)*32 + kg8;                            \
    float4 f0_ = *(const float4*)wp_;                              \
    float4 f1_ = *(const float4*)(wp_ + 4);                        \
    ux4 H_, L_;                                                    \
    H_[0] = pack2(f0_.x, f0_.y);  H_[1] = pack2(f0_.z, f0_.w);     \
    H_[2] = pack2(f1_.x, f1_.y);  H_[3] = pack2(f1_.z, f1_.w);     \
    L_[0] = pack2(lof(f0_.x), lof(f0_.y));                         \
    L_[1] = pack2(lof(f0_.z), lof(f0_.w));                         \
    L_[2] = pack2(lof(f1_.x), lof(f1_.y));                         \
    L_[3] = pack2(lof(f1_.z), lof(f1_.w));                         \
    STASH4(H0, H1, H2, H3, H_);                                    \
    STASH4(L0, L1, L2, L3, L_);                                    \
  } while (0)

// One MFMA accumulate: D/C in VGPRs, A in VGPRs, B from hard-named AGPR range.
#define MFMA4(ACC, AV, AR)                                         \
  asm volatile("v_mfma_f32_16x16x32_bf16 %0, %1, " AR ", %0"       \
               : "+v"(ACC) : "v"(AV))

#define ACLOB                                                       \
  "a0","a1","a2","a3","a4","a5","a6","a7","a8","a9","a10","a11",    \
  "a12","a13","a14","a15","a16","a17","a18","a19","a20","a21",      \
  "a22","a23","a24","a25","a26","a27","a28","a29","a30","a31",      \
  "a32","a33","a34","a35","a36","a37","a38","a39","a40","a41",      \
  "a42","a43","a44","a45","a46","a47","a48","a49","a50","a51",      \
  "a52","a53","a54","a55","a56","a57","a58","a59","a60","a61",      \
  "a62","a63","a64","a65","a66","a67","a68","a69","a70","a71",      \
  "a72","a73","a74","a75","a76","a77","a78","a79","a80","a81",      \
  "a82","a83","a84","a85","a86","a87","a88","a89","a90","a91",      \
  "a92","a93","a94","a95","a96","a97","a98","a99","a100","a101",    \
  "a102","a103","a104","a105","a106","a107","a108","a109","a110",   \
  "a111","a112","a113","a114","a115","a116","a117","a118","a119",   \
  "a120","a121","a122","a123","a124","a125","a126","a127"

// ---------------- kernel 4: MFMA-based persistent LSTM recurrence
// One block (512 thr = 8 waves) per direction. Weights -> bf16x2 hi/lo,
// packed as B-fragments of v_mfma_f32_16x16x32_bf16, parked ONCE in AGPRs
// a0..a127 (asm-managed; the allocator provably won't hold them in VGPRs,
// rounds 1-7). Per step each wave does 32 MFMA: A row0=h_hi, row1=h_lo
// (rows 2-15 junk, never read), acc = (h_hi+h_lo)(w_hi+w_lo) summed over
// rows 0+1. MFMA reads AGPRs directly -> no accvgpr_read tax (round 6).
__global__ __launch_bounds__(512) void k_lstm(
    const float* __restrict__ xp,     // [T][1024] (f cols 0:512, b cols 512:1024)
    const float* __restrict__ whh_f,  // [512][128]
    const float* __restrict__ whh_b,
    float* __restrict__ hout) {       // [T][256] (f cols 0:128, b cols 128:256)
  const int dir = blockIdx.x;
  const int tid = threadIdx.x;   // 0..511
  const int wv  = tid >> 6;      // wave 0..7
  const int ln  = tid & 63;      // lane
  const int ln15 = ln & 15;      // spatial index within fragment
  const int kg8  = (ln >> 4) * 8;  // k-subgroup offset
  const int wbase = wv * 64;     // this wave's gate-row base
  const float* __restrict__ whh = dir ? whh_b : whh_f;
  const int xofs = dir * GATES;
  const int hofs = dir * HID;

  __shared__ __align__(16) float lx[2 * 8 * GATES];     // xp ring, 32 KB
  __shared__ __align__(16) float lg[GATES];             // activated gates
  __shared__ __align__(16) unsigned short hbf[2][2][136];  // h bf16 hi/lo, dbuf

  // ---- prologue: convert + stash weight fragments into AGPRs
  FRAG(0, 0, "a0","a1","a2","a3",     "a64","a65","a66","a67");
  FRAG(0, 1, "a4","a5","a6","a7",     "a68","a69","a70","a71");
  FRAG(0, 2, "a8","a9","a10","a11",   "a72","a73","a74","a75");
  FRAG(0, 3, "a12","a13","a14","a15", "a76","a77","a78","a79");
  FRAG(1, 0, "a16","a17","a18","a19", "a80","a81","a82","a83");
  FRAG(1, 1, "a20","a21","a22","a23", "a84","a85","a86","a87");
  FRAG(1, 2, "a24","a25","a26","a27", "a88","a89","a90","a91");
  FRAG(1, 3, "a28","a29","a30","a31", "a92","a93","a94","a95");
  FRAG(2, 0, "a32","a33","a34","a35", "a96","a97","a98","a99");
  FRAG(2, 1, "a36","a37","a38","a39", "a100","a101","a102","a103");
  FRAG(2, 2, "a40","a41","a42","a43", "a104","a105","a106","a107");
  FRAG(2, 3, "a44","a45","a46","a47", "a108","a109","a110","a111");
  FRAG(3, 0, "a48","a49","a50","a51", "a112","a113","a114","a115");
  FRAG(3, 1, "a52","a53","a54","a55", "a116","a117","a118","a119");
  FRAG(3, 2, "a56","a57","a58","a59", "a120","a121","a122","a123");
  FRAG(3, 3, "a60","a61","a62","a63", "a124","a125","a126","a127");

  // ---- stage xp group 0 into ring buffer 0; thread covers 8 floats
  const int xu = tid >> 6;          // step-in-group 0..7
  const int xc = (tid & 63) * 8;    // col 0..504
  {
    const int tt = dir ? (T_SEQ - 1 - xu) : xu;
    const float* gp = xp + (size_t)tt * XPD + xofs + xc;
    *(fx4*)&lx[tid * 8]     = *(const fx4*)gp;
    *(fx4*)&lx[tid * 8 + 4] = *(const fx4*)(gp + 4);
  }
  float c = 0.0f;
  if (tid < HID) {
    hbf[0][0][tid] = 0; hbf[0][1][tid] = 0;
  }
  __syncthreads();

  int buf = 0;
  for (int t0 = 0; t0 < T_SEQ; t0 += 8) {
    // issue next group's xp loads via raw asm (no implicit waits; drained
    // by the explicit vmcnt(0) at u==7)
    const int tb = (t0 + 8 < T_SEQ) ? t0 + 8 : 0;
    fx4 xr0, xr1;
    {
      const int tg = tb + xu;
      const int tt = dir ? (T_SEQ - 1 - tg) : tg;
      const float* gp = xp + (size_t)tt * XPD + xofs + xc;
      asm volatile("global_load_dwordx4 %0, %2, off\n\t"
                   "global_load_dwordx4 %1, %2, off offset:16"
                   : "=&v"(xr0), "=&v"(xr1) : "v"(gp));
    }
    const float* lxb = lx + buf * (8 * GATES);
#pragma unroll
    for (int u = 0; u < 8; ++u) {
      const int t = t0 + u;
      const int tt = dir ? (T_SEQ - 1 - t) : t;
      const int p = t & 1;
      // A-fragments: row0 lanes read h_hi, row1 lanes h_lo, rows 2-15 read
      // h_hi too (their products land in acc rows 2-15, which are never read)
      const unsigned short* ap = (ln15 == 1 ? &hbf[p][1][0] : &hbf[p][0][0]) + kg8;
      ux4 av0 = *(const ux4*)(ap);
      ux4 av1 = *(const ux4*)(ap + 32);
      ux4 av2 = *(const ux4*)(ap + 64);
      ux4 av3 = *(const ux4*)(ap + 96);
      fx4 acc0 = {0.f, 0.f, 0.f, 0.f};
      fx4 acc1 = {0.f, 0.f, 0.f, 0.f};
      fx4 acc2 = {0.f, 0.f, 0.f, 0.f};
      fx4 acc3 = {0.f, 0.f, 0.f, 0.f};
      // VALU(acc init) -> MFMA srcC hazard cover + RA keep-out of a0..a127
      asm volatile("s_nop 1"
                   : "+v"(acc0), "+v"(acc1), "+v"(acc2), "+v"(acc3)
                   :: ACLOB);
      MFMA4(acc0, av0, "a[0:3]");
      MFMA4(acc1, av0, "a[16:19]");
      MFMA4(acc2, av0, "a[32:35]");
      MFMA4(acc3, av0, "a[48:51]");
      MFMA4(acc0, av1, "a[4:7]");
      MFMA4(acc1, av1, "a[20:23]");
      MFMA4(acc2, av1, "a[36:39]");
      MFMA4(acc3, av1, "a[52:55]");
      MFMA4(acc0, av2, "a[8:11]");
      MFMA4(acc1, av2, "a[24:27]");
      MFMA4(acc2, av2, "a[40:43]");
      MFMA4(acc3, av2, "a[56:59]");
      MFMA4(acc0, av3, "a[12:15]");
      MFMA4(acc1, av3, "a[28:31]");
      MFMA4(acc2, av3, "a[44:47]");
      MFMA4(acc3, av3, "a[60:63]");
      MFMA4(acc0, av0, "a[64:67]");
      MFMA4(acc1, av0, "a[80:83]");
      MFMA4(acc2, av0, "a[96:99]");
      MFMA4(acc3, av0, "a[112:115]");
      MFMA4(acc0, av1, "a[68:71]");
      MFMA4(acc1, av1, "a[84:87]");
      MFMA4(acc2, av1, "a[100:103]");
      MFMA4(acc3, av1, "a[116:119]");
      MFMA4(acc0, av2, "a[72:75]");
      MFMA4(acc1, av2, "a[88:91]");
      MFMA4(acc2, av2, "a[104:107]");
      MFMA4(acc3, av2, "a[120:123]");
      MFMA4(acc0, av3, "a[76:79]");
      MFMA4(acc1, av3, "a[92:95]");
      MFMA4(acc2, av3, "a[108:111]");
      MFMA4(acc3, av3, "a[124:127]");
      // MFMA -> VALU read hazard cover; pins the acc reads after the nops
      asm volatile("s_nop 7\n\ts_nop 7\n\ts_nop 7"
                   : "+v"(acc0), "+v"(acc1), "+v"(acc2), "+v"(acc3));
      // extraction (lanes 0-15 hold real data): gate = row0 + row1 + xp
      float g0 = acc0[0] + acc0[1] + lxb[u * GATES + wbase +  0 + ln15];
      float g1 = acc1[0] + acc1[1] + lxb[u * GATES + wbase + 16 + ln15];
      float g2 = acc2[0] + acc2[1] + lxb[u * GATES + wbase + 32 + ln15];
      float g3 = acc3[0] + acc3[1] + lxb[u * GATES + wbase + 48 + ln15];
      const int cls = wv >> 1;  // 0=i 1=f 2=g 3=o (wave-uniform)
      float a0, a1, a2, a3;
      if (cls == 2) {
        a0 = tanh_f(g0); a1 = tanh_f(g1); a2 = tanh_f(g2); a3 = tanh_f(g3);
      } else {
        a0 = sigm(g0);   a1 = sigm(g1);   a2 = sigm(g2);   a3 = sigm(g3);
      }
      if (ln < 16) {
        lg[wbase +  0 + ln] = a0;
        lg[wbase + 16 + ln] = a1;
        lg[wbase + 32 + ln] = a2;
        lg[wbase + 48 + ln] = a3;
      }
      asm volatile("s_waitcnt lgkmcnt(0)" ::: "memory");
      __builtin_amdgcn_s_barrier();
      if (tid < HID) {
        float gi = lg[tid];
        float gf = lg[HID + tid];
        float gg = lg[2 * HID + tid];
        float go = lg[3 * HID + tid];
        c = gf * c + gi * gg;
        float h = go * tanh_f(c);
        unsigned int hh = f2bf1(h);
        float hr = h - bf2f(hh);
        hbf[p ^ 1][0][tid] = (unsigned short)hh;
        hbf[p ^ 1][1][tid] = (unsigned short)f2bf1(hr);
        hout[(size_t)tt * 256 + hofs + tid] = h;  // fire-and-forget
      }
      if (u == 7) {
        asm volatile("s_waitcnt vmcnt(0)" ::: "memory");
        *(fx4*)&lx[(buf ^ 1) * (8 * GATES) + tid * 8]     = xr0;
        *(fx4*)&lx[(buf ^ 1) * (8 * GATES) + tid * 8 + 4] = xr1;
      }
      asm volatile("s_waitcnt lgkmcnt(0)" ::: "memory");
      __builtin_amdgcn_s_barrier();
    }
    buf ^= 1;
  }
}

// ---------------- kernel 5: tag_space = h2 @ W_out^T + b_out
__global__ void k_out(const float* __restrict__ h2,
                      const float* __restrict__ Wout,
                      const float* __restrict__ bout,
                      float* __restrict__ out) {
  __shared__ __align__(16) float hrow[256];
  const int t = blockIdx.x;
  const int tid = threadIdx.x;  // 64
  *(float4*)&hrow[tid * 4] = *(const float4*)&h2[(size_t)t * 256 + tid * 4];
  __syncthreads();
  if (tid < TAGS) {
    float acc = bout[tid];
    const float* w = &Wout[(size_t)tid * 256];
#pragma unroll 8
    for (int k = 0; k < 256; k += 4) {
      float4 wv = *(const float4*)&w[k];
      acc += hrow[k] * wv.x + hrow[k + 1] * wv.y + hrow[k + 2] * wv.z +
             hrow[k + 3] * wv.w;
    }
    out[(size_t)t * TAGS + tid] = acc;
  }
}

extern "C" void kernel_launch(void* const* d_in, const int* in_sizes, int n_in,
                              void* d_out, int out_size, void* d_ws, size_t ws_size,
                              hipStream_t stream) {
  const int*   morp_ids = (const int*)d_in[0];
  const int*   seg      = (const int*)d_in[1];
  const int*   pred_idx = (const int*)d_in[2];
  const int*   dp_in    = (const int*)d_in[3];
  const float* feat     = (const float*)d_in[4];
  const float* W_wv     = (const float*)d_in[5];
  const float* dp_table = (const float*)d_in[6];
  const float* W_out    = (const float*)d_in[7];
  const float* b_out    = (const float*)d_in[8];
  const float* w_ih_l0f = (const float*)d_in[9];
  const float* w_hh_l0f = (const float*)d_in[10];
  const float* b_l0f    = (const float*)d_in[11];
  const float* w_ih_l0b = (const float*)d_in[12];
  const float* w_hh_l0b = (const float*)d_in[13];
  const float* b_l0b    = (const float*)d_in[14];
  const float* w_ih_l1f = (const float*)d_in[15];
  const float* w_hh_l1f = (const float*)d_in[16];
  const float* b_l1f    = (const float*)d_in[17];
  const float* w_ih_l1b = (const float*)d_in[18];
  const float* w_hh_l1b = (const float*)d_in[19];
  const float* b_l1b    = (const float*)d_in[20];
  float* out = (float*)d_out;

  float* ws  = (float*)d_ws;
  float* inp = ws;                      // 2048*304
  float* xp  = inp + 2048 * LDA0;       // 2048*1024 (reused for both layers)
  float* h1  = xp + 2048 * XPD;         // 2048*256
  float* h2  = h1 + 2048 * 256;         // 2048*256

  k_toksum<<<2048, 128, 0, stream>>>(W_wv, morp_ids, seg, inp);
  k_fill<<<2048, 256, 0, stream>>>(dp_table, dp_in, feat, pred_idx, inp);

  dim3 gg(32, 16);
  k_gemm<<<gg, 256, 0, stream>>>(inp, LDA0, 300, w_ih_l0f, w_ih_l0b, b_l0f, b_l0b, xp);
  k_lstm<<<2, 512, 0, stream>>>(xp, w_hh_l0f, w_hh_l0b, h1);
  k_gemm<<<gg, 256, 0, stream>>>(h1, 256, 256, w_ih_l1f, w_ih_l1b, b_l1f, b_l1b, xp);
  k_lstm<<<2, 512, 0, stream>>>(xp, w_hh_l1f, w_hh_l1b, h2);
  k_out<<<2048, 64, 0, stream>>>(h2, W_out, b_out, out);
}

// Round 10
// 3782.182 us; speedup vs baseline: 1.4179x; 1.0675x over previous
//
#include <hip/hip_runtime.h>

#define T_SEQ 2048
#define NMORPH 6144
#define EMB 100
#define HID 128
#define GATES 512
#define LDA0 304
#define XPD 1024
#define TAGS 50

typedef float  fx4 __attribute__((ext_vector_type(4)));
typedef unsigned int ux4 __attribute__((ext_vector_type(4)));

__device__ __forceinline__ float sigm(float x) {
  return 1.0f / (1.0f + __expf(-x));
}
__device__ __forceinline__ float tanh_f(float x) {
  x = fminf(fmaxf(x, -9.0f), 9.0f);
  float e2 = __expf(2.0f * x);
  return (e2 - 1.0f) / (e2 + 1.0f);
}
// round-to-nearest-even fp32 -> bf16 (as uint), and back
__device__ __forceinline__ unsigned int f2bf1(float x) {
  unsigned int u = __float_as_uint(x);
  return (u + 0x7FFFu + ((u >> 16) & 1u)) >> 16;
}
__device__ __forceinline__ float bf2f(unsigned int h) {
  return __uint_as_float(h << 16);
}
__device__ __forceinline__ unsigned int pack2(float a, float b) {
  return f2bf1(a) | (f2bf1(b) << 16);
}
__device__ __forceinline__ float lof(float x) {
  return x - bf2f(f2bf1(x));
}

// ---------------- kernel 1: segment-sum of morpheme embeddings into inp[:,0:100]
__global__ void k_toksum(const float* __restrict__ W_wv,
                         const int* __restrict__ morp_ids,
                         const int* __restrict__ seg,
                         float* __restrict__ inp) {
  const int t = blockIdx.x;
  const int d = threadIdx.x;  // 0..127
  int a = 0, b = NMORPH;
  while (a < b) { int m = (a + b) >> 1; if (seg[m] < t) a = m + 1; else b = m; }
  const int lo = a;
  b = NMORPH;
  while (a < b) { int m = (a + b) >> 1; if (seg[m] <= t) a = m + 1; else b = m; }
  const int hi = a;
  if (d < EMB) {
    float s = 0.0f;
    for (int m = lo; m < hi; ++m)
      s += W_wv[(size_t)morp_ids[m] * EMB + d];
    inp[(size_t)t * LDA0 + d] = s;
  }
}

// ---------------- kernel 2: fill inp cols 100..303 (pred vec, dp emb, feat, pad)
__global__ void k_fill(const float* __restrict__ dp_table,
                       const int* __restrict__ dp_in,
                       const float* __restrict__ feat,
                       const int* __restrict__ pred_idx,
                       float* __restrict__ inp) {
  const int t = blockIdx.x;
  const int c = threadIdx.x;  // 0..255 -> col 100+c
  if (c >= 204) return;
  const int col = 100 + c;
  float v;
  if (col < 200)      v = inp[(size_t)pred_idx[0] * LDA0 + (col - 100)];
  else if (col < 264) v = dp_table[dp_in[t] * 64 + (col - 200)];
  else if (col < 300) v = feat[t * 36 + (col - 264)];
  else                v = 0.0f;  // pad cols 300..303
  inp[(size_t)t * LDA0 + col] = v;
}

// ---------------- kernel 3: xp[M x 1024] = A[M x K] @ [Wf;Wb]^T + [bf;bb]
__global__ __launch_bounds__(256) void k_gemm(
    const float* __restrict__ A, int lda, int K,
    const float* __restrict__ Wf, const float* __restrict__ Wb,
    const float* __restrict__ bf, const float* __restrict__ bb,
    float* __restrict__ out) {
  constexpr int BK = 16, LDT = 68;
  __shared__ float As[BK][LDT];
  __shared__ float Bs[BK][LDT];
  const int tid = threadIdx.x;
  const int tx = tid & 15, ty = tid >> 4;
  const int bm = blockIdx.x * 64;
  const int n0 = blockIdx.y * 64;
  const float* __restrict__ W  = (n0 < GATES) ? Wf : Wb;
  const float* __restrict__ bs = (n0 < GATES) ? bf : bb;
  const int nw = (n0 < GATES) ? n0 : n0 - GATES;
  const int ar = tid >> 2;
  const int ak = (tid & 3) * 4;
  float acc[4][4] = {};
  const int ktiles = (K + BK - 1) / BK;
  for (int kt = 0; kt < ktiles; ++kt) {
    const int k0 = kt * BK;
    float4 av = *(const float4*)&A[(size_t)(bm + ar) * lda + k0 + ak];
    float4 bv = make_float4(0.f, 0.f, 0.f, 0.f);
    if (k0 + ak < K)
      bv = *(const float4*)&W[(size_t)(nw + ar) * K + k0 + ak];
    __syncthreads();
    As[ak + 0][ar] = av.x; As[ak + 1][ar] = av.y;
    As[ak + 2][ar] = av.z; As[ak + 3][ar] = av.w;
    Bs[ak + 0][ar] = bv.x; Bs[ak + 1][ar] = bv.y;
    Bs[ak + 2][ar] = bv.z; Bs[ak + 3][ar] = bv.w;
    __syncthreads();
#pragma unroll
    for (int kk = 0; kk < BK; ++kk) {
      float4 a4 = *(const float4*)&As[kk][ty * 4];
      float4 b4 = *(const float4*)&Bs[kk][tx * 4];
      float a_[4] = {a4.x, a4.y, a4.z, a4.w};
      float b_[4] = {b4.x, b4.y, b4.z, b4.w};
#pragma unroll
      for (int i = 0; i < 4; ++i)
#pragma unroll
        for (int j = 0; j < 4; ++j)
          acc[i][j] = fmaf(a_[i], b_[j], acc[i][j]);
    }
  }
  const float4 bias4 = *(const float4*)&bs[nw + tx * 4];
#pragma unroll
  for (int i = 0; i < 4; ++i) {
    float4 o;
    o.x = acc[i][0] + bias4.x;
    o.y = acc[i][1] + bias4.y;
    o.z = acc[i][2] + bias4.z;
    o.w = acc[i][3] + bias4.w;
    *(float4*)&out[(size_t)(bm + ty * 4 + i) * XPD + n0 + tx * 4] = o;
  }
}

// Stash one packed bf16x8 fragment (4 dwords) into hard-named AGPRs.
#define STASH4(A0, A1, A2, A3, V)                                  \
  asm volatile("v_accvgpr_write_b32 " A0 ", %0\n\t"                \
               "v_accvgpr_write_b32 " A1 ", %1\n\t"                \
               "v_accvgpr_write_b32 " A2 ", %2\n\t"                \
               "v_accvgpr_write_b32 " A3 ", %3"                    \
               :: "v"(V[0]), "v"(V[1]), "v"(V[2]), "v"(V[3])       \
               : A0, A1, A2, A3)

// Load 8 fp32 weights, split into bf16 hi/lo, pack, stash hi+lo fragments.
// Row mapping (round 10): tile TN = gate class; this wave covers hidden
// units [wv*16, wv*16+16), so weight row = TN*128 + wv*16 + ln15.
#define FRAG(TN, KC, H0,H1,H2,H3, L0,L1,L2,L3)                     \
  do {                                                             \
    const float* wp_ = whh + (size_t)((TN)*128 + wtile + ln15)*HID \
                       + (KC)*32 + kg8;                            \
    float4 f0_ = *(const float4*)wp_;                              \
    float4 f1_ = *(const float4*)(wp_ + 4);                        \
    ux4 H_, L_;                                                    \
    H_[0] = pack2(f0_.x, f0_.y);  H_[1] = pack2(f0_.z, f0_.w);     \
    H_[2] = pack2(f1_.x, f1_.y);  H_[3] = pack2(f1_.z, f1_.w);     \
    L_[0] = pack2(lof(f0_.x), lof(f0_.y));                         \
    L_[1] = pack2(lof(f0_.z), lof(f0_.w));                         \
    L_[2] = pack2(lof(f1_.x), lof(f1_.y));                         \
    L_[3] = pack2(lof(f1_.z), lof(f1_.w));                         \
    STASH4(H0, H1, H2, H3, H_);                                    \
    STASH4(L0, L1, L2, L3, L_);                                    \
  } while (0)

// One MFMA accumulate: D/C in VGPRs, A in VGPRs, B from hard-named AGPR range.
#define MFMA4(ACC, AV, AR)                                         \
  asm volatile("v_mfma_f32_16x16x32_bf16 %0, %1, " AR ", %0"       \
               : "+v"(ACC) : "v"(AV))

#define ACLOB                                                       \
  "a0","a1","a2","a3","a4","a5","a6","a7","a8","a9","a10","a11",    \
  "a12","a13","a14","a15","a16","a17","a18","a19","a20","a21",      \
  "a22","a23","a24","a25","a26","a27","a28","a29","a30","a31",      \
  "a32","a33","a34","a35","a36","a37","a38","a39","a40","a41",      \
  "a42","a43","a44","a45","a46","a47","a48","a49","a50","a51",      \
  "a52","a53","a54","a55","a56","a57","a58","a59","a60","a61",      \
  "a62","a63","a64","a65","a66","a67","a68","a69","a70","a71",      \
  "a72","a73","a74","a75","a76","a77","a78","a79","a80","a81",      \
  "a82","a83","a84","a85","a86","a87","a88","a89","a90","a91",      \
  "a92","a93","a94","a95","a96","a97","a98","a99","a100","a101",    \
  "a102","a103","a104","a105","a106","a107","a108","a109","a110",   \
  "a111","a112","a113","a114","a115","a116","a117","a118","a119",   \
  "a120","a121","a122","a123","a124","a125","a126","a127"

// ---------------- kernel 4: MFMA persistent LSTM, single barrier per step
// 512 thr = 8 waves per direction. Wave w owns ALL FOUR gates of hidden
// units [16w,16w+16) -> i,f,g,o land in-wave after MFMA, c/h update is
// in-register: no lg buffer, ONE barrier + ONE LDS round trip (h) per step.
// Weights (bf16 hi/lo split) parked in AGPRs a0..a127. 8 acc chains of
// depth 4. acc[0] init = xp addend (saves zero-init + add); acc[2:3] never
// re-zeroed (junk rows, never read).
__global__ __launch_bounds__(512) void k_lstm(
    const float* __restrict__ xp,     // [T][1024] (f cols 0:512, b cols 512:1024)
    const float* __restrict__ whh_f,  // [512][128]
    const float* __restrict__ whh_b,
    float* __restrict__ hout) {       // [T][256] (f cols 0:128, b cols 128:256)
  const int dir = blockIdx.x;
  const int tid = threadIdx.x;   // 0..511
  const int wv  = tid >> 6;      // wave 0..7
  const int ln  = tid & 63;      // lane
  const int ln15 = ln & 15;      // spatial index within fragment
  const int kg8  = (ln >> 4) * 8;  // k-subgroup offset
  const int wtile = wv * 16;     // this wave's hidden-unit base
  const float* __restrict__ whh = dir ? whh_b : whh_f;
  const int xofs = dir * GATES;
  const int hofs = dir * HID;

  __shared__ __align__(16) float lx[2 * 8 * GATES];        // xp ring, 32 KB
  __shared__ __align__(16) unsigned short hbf[2][2][136];  // h bf16 hi/lo, dbuf

  // ---- prologue: convert + stash weight fragments into AGPRs
  FRAG(0, 0, "a0","a1","a2","a3",     "a64","a65","a66","a67");
  FRAG(0, 1, "a4","a5","a6","a7",     "a68","a69","a70","a71");
  FRAG(0, 2, "a8","a9","a10","a11",   "a72","a73","a74","a75");
  FRAG(0, 3, "a12","a13","a14","a15", "a76","a77","a78","a79");
  FRAG(1, 0, "a16","a17","a18","a19", "a80","a81","a82","a83");
  FRAG(1, 1, "a20","a21","a22","a23", "a84","a85","a86","a87");
  FRAG(1, 2, "a24","a25","a26","a27", "a88","a89","a90","a91");
  FRAG(1, 3, "a28","a29","a30","a31", "a92","a93","a94","a95");
  FRAG(2, 0, "a32","a33","a34","a35", "a96","a97","a98","a99");
  FRAG(2, 1, "a36","a37","a38","a39", "a100","a101","a102","a103");
  FRAG(2, 2, "a40","a41","a42","a43", "a104","a105","a106","a107");
  FRAG(2, 3, "a44","a45","a46","a47", "a108","a109","a110","a111");
  FRAG(3, 0, "a48","a49","a50","a51", "a112","a113","a114","a115");
  FRAG(3, 1, "a52","a53","a54","a55", "a116","a117","a118","a119");
  FRAG(3, 2, "a56","a57","a58","a59", "a120","a121","a122","a123");
  FRAG(3, 3, "a60","a61","a62","a63", "a124","a125","a126","a127");

  // ---- stage xp group 0 into ring buffer 0; thread covers 8 floats
  const int xu = tid >> 6;          // step-in-group 0..7
  const int xc = (tid & 63) * 8;    // col 0..504
  {
    const int tt = dir ? (T_SEQ - 1 - xu) : xu;
    const float* gp = xp + (size_t)tt * XPD + xofs + xc;
    *(fx4*)&lx[tid * 8]     = *(const fx4*)gp;
    *(fx4*)&lx[tid * 8 + 4] = *(const fx4*)(gp + 4);
  }
  float c = 0.0f;
  if (tid < HID) {
    hbf[0][0][tid] = 0; hbf[0][1][tid] = 0;
  }
  // per-thread incremental hout pointer (unit wtile+ln15)
  float* hp = hout + (size_t)(dir ? (T_SEQ - 1) : 0) * 256 + hofs + wtile + ln15;
  const ptrdiff_t hstep = dir ? -256 : 256;

  // accumulators persist across steps; [2],[3] accumulate junk rows forever
  fx4 ah0 = {0,0,0,0}, ah1 = {0,0,0,0}, ah2 = {0,0,0,0}, ah3 = {0,0,0,0};
  fx4 al0 = {0,0,0,0}, al1 = {0,0,0,0}, al2 = {0,0,0,0}, al3 = {0,0,0,0};

  __syncthreads();

  int buf = 0;
  for (int t0 = 0; t0 < T_SEQ; t0 += 8) {
    // issue next group's xp loads via raw asm (drained at u==7 vmcnt(0))
    const int tb = (t0 + 8 < T_SEQ) ? t0 + 8 : 0;
    fx4 xr0, xr1;
    {
      const int tg = tb + xu;
      const int tt = dir ? (T_SEQ - 1 - tg) : tg;
      const float* gp = xp + (size_t)tt * XPD + xofs + xc;
      asm volatile("global_load_dwordx4 %0, %2, off\n\t"
                   "global_load_dwordx4 %1, %2, off offset:16"
                   : "=&v"(xr0), "=&v"(xr1) : "v"(gp));
    }
    const float* lxb = lx + buf * (8 * GATES);
#pragma unroll
    for (int u = 0; u < 8; ++u) {
      const int p = u & 1;  // t0 is even -> parity is compile-time per u
      // xp addends for this step (4 broadcast ds_read_b32 / read2)
      const float* xrow = lxb + u * GATES + wtile + ln15;
      float x_i = xrow[0];
      float x_f = xrow[128];
      float x_g = xrow[256];
      float x_o = xrow[384];
      // A-fragments from hbf[p]: row0 lanes h_hi, row1 lanes h_lo
      const unsigned short* ap =
          (ln15 == 1 ? &hbf[p][1][0] : &hbf[p][0][0]) + kg8;
      ux4 av0 = *(const ux4*)(ap);
      ux4 av1 = *(const ux4*)(ap + 32);
      ux4 av2 = *(const ux4*)(ap + 64);
      ux4 av3 = *(const ux4*)(ap + 96);
      // acc init: [0] = xp addend, [1] = 0; [2],[3] untouched junk
      ah0[0] = x_i; ah0[1] = 0.f;
      ah1[0] = x_f; ah1[1] = 0.f;
      ah2[0] = x_g; ah2[1] = 0.f;
      ah3[0] = x_o; ah3[1] = 0.f;
      al0[0] = 0.f; al0[1] = 0.f;
      al1[0] = 0.f; al1[1] = 0.f;
      al2[0] = 0.f; al2[1] = 0.f;
      al3[0] = 0.f; al3[1] = 0.f;
      // VALU->MFMA srcC hazard cover + RA keep-out of a0..a127
      asm volatile("s_nop 1"
                   : "+v"(ah0), "+v"(ah1), "+v"(ah2), "+v"(ah3),
                     "+v"(al0), "+v"(al1), "+v"(al2), "+v"(al3)
                   :: ACLOB);
      // 32 MFMA: 8 independent chains x 4 k-chunks
      MFMA4(ah0, av0, "a[0:3]");
      MFMA4(ah1, av0, "a[16:19]");
      MFMA4(ah2, av0, "a[32:35]");
      MFMA4(ah3, av0, "a[48:51]");
      MFMA4(al0, av0, "a[64:67]");
      MFMA4(al1, av0, "a[80:83]");
      MFMA4(al2, av0, "a[96:99]");
      MFMA4(al3, av0, "a[112:115]");
      MFMA4(ah0, av1, "a[4:7]");
      MFMA4(ah1, av1, "a[20:23]");
      MFMA4(ah2, av1, "a[36:39]");
      MFMA4(ah3, av1, "a[52:55]");
      MFMA4(al0, av1, "a[68:71]");
      MFMA4(al1, av1, "a[84:87]");
      MFMA4(al2, av1, "a[100:103]");
      MFMA4(al3, av1, "a[116:119]");
      MFMA4(ah0, av2, "a[8:11]");
      MFMA4(ah1, av2, "a[24:27]");
      MFMA4(ah2, av2, "a[40:43]");
      MFMA4(ah3, av2, "a[56:59]");
      MFMA4(al0, av2, "a[72:75]");
      MFMA4(al1, av2, "a[88:91]");
      MFMA4(al2, av2, "a[104:107]");
      MFMA4(al3, av2, "a[120:123]");
      MFMA4(ah0, av3, "a[12:15]");
      MFMA4(ah1, av3, "a[28:31]");
      MFMA4(ah2, av3, "a[44:47]");
      MFMA4(ah3, av3, "a[60:63]");
      MFMA4(al0, av3, "a[76:79]");
      MFMA4(al1, av3, "a[92:95]");
      MFMA4(al2, av3, "a[108:111]");
      MFMA4(al3, av3, "a[124:127]");
      // MFMA -> VALU read hazard cover
      asm volatile("s_nop 7\n\ts_nop 7\n\ts_nop 7"
                   : "+v"(ah0), "+v"(ah1), "+v"(ah2), "+v"(ah3),
                     "+v"(al0), "+v"(al1), "+v"(al2), "+v"(al3));
      // extraction (rows 0,1 live on lanes 0-15) + activation + update
      float i_g = sigm(ah0[0] + ah0[1] + al0[0] + al0[1]);
      float f_g = sigm(ah1[0] + ah1[1] + al1[0] + al1[1]);
      float g_g = tanh_f(ah2[0] + ah2[1] + al2[0] + al2[1]);
      float o_g = sigm(ah3[0] + ah3[1] + al3[0] + al3[1]);
      c = f_g * c + i_g * g_g;
      float h = o_g * tanh_f(c);
      if (ln < 16) {
        unsigned int hh = f2bf1(h);
        float hr = h - bf2f(hh);
        hbf[p ^ 1][0][wtile + ln15] = (unsigned short)hh;
        hbf[p ^ 1][1][wtile + ln15] = (unsigned short)f2bf1(hr);
        *hp = h;  // fire-and-forget global store
      }
      hp += hstep;
      if (u == 7) {
        asm volatile("s_waitcnt vmcnt(0)" ::: "memory");
        *(fx4*)&lx[(buf ^ 1) * (8 * GATES) + tid * 8]     = xr0;
        *(fx4*)&lx[(buf ^ 1) * (8 * GATES) + tid * 8 + 4] = xr1;
      }
      asm volatile("s_waitcnt lgkmcnt(0)" ::: "memory");
      __builtin_amdgcn_s_barrier();
    }
    buf ^= 1;
  }
}

// ---------------- kernel 5: tag_space = h2 @ W_out^T + b_out
__global__ void k_out(const float* __restrict__ h2,
                      const float* __restrict__ Wout,
                      const float* __restrict__ bout,
                      float* __restrict__ out) {
  __shared__ __align__(16) float hrow[256];
  const int t = blockIdx.x;
  const int tid = threadIdx.x;  // 64
  *(float4*)&hrow[tid * 4] = *(const float4*)&h2[(size_t)t * 256 + tid * 4];
  __syncthreads();
  if (tid < TAGS) {
    float acc = bout[tid];
    const float* w = &Wout[(size_t)tid * 256];
#pragma unroll 8
    for (int k = 0; k < 256; k += 4) {
      float4 wv = *(const float4*)&w[k];
      acc += hrow[k] * wv.x + hrow[k + 1] * wv.y + hrow[k + 2] * wv.z +
             hrow[k + 3] * wv.w;
    }
    out[(size_t)t * TAGS + tid] = acc;
  }
}

extern "C" void kernel_launch(void* const* d_in, const int* in_sizes, int n_in,
                              void* d_out, int out_size, void* d_ws, size_t ws_size,
                              hipStream_t stream) {
  const int*   morp_ids = (const int*)d_in[0];
  const int*   seg      = (const int*)d_in[1];
  const int*   pred_idx = (const int*)d_in[2];
  const int*   dp_in    = (const int*)d_in[3];
  const float* feat     = (const float*)d_in[4];
  const float* W_wv     = (const float*)d_in[5];
  const float* dp_table = (const float*)d_in[6];
  const float* W_out    = (const float*)d_in[7];
  const float* b_out    = (const float*)d_in[8];
  const float* w_ih_l0f = (const float*)d_in[9];
  const float* w_hh_l0f = (const float*)d_in[10];
  const float* b_l0f    = (const float*)d_in[11];
  const float* w_ih_l0b = (const float*)d_in[12];
  const float* w_hh_l0b = (const float*)d_in[13];
  const float* b_l0b    = (const float*)d_in[14];
  const float* w_ih_l1f = (const float*)d_in[15];
  const float* w_hh_l1f = (const float*)d_in[16];
  const float* b_l1f    = (const float*)d_in[17];
  const float* w_ih_l1b = (const float*)d_in[18];
  const float* w_hh_l1b = (const float*)d_in[19];
  const float* b_l1b    = (const float*)d_in[20];
  float* out = (float*)d_out;

  float* ws  = (float*)d_ws;
  float* inp = ws;                      // 2048*304
  float* xp  = inp + 2048 * LDA0;       // 2048*1024 (reused for both layers)
  float* h1  = xp + 2048 * XPD;         // 2048*256
  float* h2  = h1 + 2048 * 256;         // 2048*256

  k_toksum<<<2048, 128, 0, stream>>>(W_wv, morp_ids, seg, inp);
  k_fill<<<2048, 256, 0, stream>>>(dp_table, dp_in, feat, pred_idx, inp);

  dim3 gg(32, 16);
  k_gemm<<<gg, 256, 0, stream>>>(inp, LDA0, 300, w_ih_l0f, w_ih_l0b, b_l0f, b_l0b, xp);
  k_lstm<<<2, 512, 0, stream>>>(xp, w_hh_l0f, w_hh_l0b, h1);
  k_gemm<<<gg, 256, 0, stream>>>(h1, 256, 256, w_ih_l1f, w_ih_l1b, b_l1f, b_l1b, xp);
  k_lstm<<<2, 512, 0, stream>>>(xp, w_hh_l1f, w_hh_l1b, h2);
  k_out<<<2048, 64, 0, stream>>>(h2, W_out, b_out, out);
}

// Round 11
// 3745.710 us; speedup vs baseline: 1.4317x; 1.0097x over previous
//
#include <hip/hip_runtime.h>

#define T_SEQ 2048
#define NMORPH 6144
#define EMB 100
#define HID 128
#define GATES 512
#define LDA0 304
#define XPD 1024
#define TAGS 50

typedef float  fx4 __attribute__((ext_vector_type(4)));
typedef unsigned int ux4 __attribute__((ext_vector_type(4)));

__device__ __forceinline__ float sigm(float x) {
  return 1.0f / (1.0f + __expf(-x));
}
__device__ __forceinline__ float tanh_f(float x) {
  x = fminf(fmaxf(x, -9.0f), 9.0f);
  float e2 = __expf(2.0f * x);
  return (e2 - 1.0f) / (e2 + 1.0f);
}
// round-to-nearest-even fp32 -> bf16 (as uint), and back
__device__ __forceinline__ unsigned int f2bf1(float x) {
  unsigned int u = __float_as_uint(x);
  return (u + 0x7FFFu + ((u >> 16) & 1u)) >> 16;
}
__device__ __forceinline__ float bf2f(unsigned int h) {
  return __uint_as_float(h << 16);
}
__device__ __forceinline__ unsigned int pack2(float a, float b) {
  return f2bf1(a) | (f2bf1(b) << 16);
}
__device__ __forceinline__ float lof(float x) {
  return x - bf2f(f2bf1(x));
}

// ---------------- kernel 1: segment-sum of morpheme embeddings into inp[:,0:100]
__global__ void k_toksum(const float* __restrict__ W_wv,
                         const int* __restrict__ morp_ids,
                         const int* __restrict__ seg,
                         float* __restrict__ inp) {
  const int t = blockIdx.x;
  const int d = threadIdx.x;  // 0..127
  int a = 0, b = NMORPH;
  while (a < b) { int m = (a + b) >> 1; if (seg[m] < t) a = m + 1; else b = m; }
  const int lo = a;
  b = NMORPH;
  while (a < b) { int m = (a + b) >> 1; if (seg[m] <= t) a = m + 1; else b = m; }
  const int hi = a;
  if (d < EMB) {
    float s = 0.0f;
    for (int m = lo; m < hi; ++m)
      s += W_wv[(size_t)morp_ids[m] * EMB + d];
    inp[(size_t)t * LDA0 + d] = s;
  }
}

// ---------------- kernel 2: fill inp cols 100..303 (pred vec, dp emb, feat, pad)
__global__ void k_fill(const float* __restrict__ dp_table,
                       const int* __restrict__ dp_in,
                       const float* __restrict__ feat,
                       const int* __restrict__ pred_idx,
                       float* __restrict__ inp) {
  const int t = blockIdx.x;
  const int c = threadIdx.x;  // 0..255 -> col 100+c
  if (c >= 204) return;
  const int col = 100 + c;
  float v;
  if (col < 200)      v = inp[(size_t)pred_idx[0] * LDA0 + (col - 100)];
  else if (col < 264) v = dp_table[dp_in[t] * 64 + (col - 200)];
  else if (col < 300) v = feat[t * 36 + (col - 264)];
  else                v = 0.0f;  // pad cols 300..303
  inp[(size_t)t * LDA0 + col] = v;
}

// ---------------- kernel 3: xp[M x 1024] = A[M x K] @ [Wf;Wb]^T + [bf;bb]
__global__ __launch_bounds__(256) void k_gemm(
    const float* __restrict__ A, int lda, int K,
    const float* __restrict__ Wf, const float* __restrict__ Wb,
    const float* __restrict__ bf, const float* __restrict__ bb,
    float* __restrict__ out) {
  constexpr int BK = 16, LDT = 68;
  __shared__ float As[BK][LDT];
  __shared__ float Bs[BK][LDT];
  const int tid = threadIdx.x;
  const int tx = tid & 15, ty = tid >> 4;
  const int bm = blockIdx.x * 64;
  const int n0 = blockIdx.y * 64;
  const float* __restrict__ W  = (n0 < GATES) ? Wf : Wb;
  const float* __restrict__ bs = (n0 < GATES) ? bf : bb;
  const int nw = (n0 < GATES) ? n0 : n0 - GATES;
  const int ar = tid >> 2;
  const int ak = (tid & 3) * 4;
  float acc[4][4] = {};
  const int ktiles = (K + BK - 1) / BK;
  for (int kt = 0; kt < ktiles; ++kt) {
    const int k0 = kt * BK;
    float4 av = *(const float4*)&A[(size_t)(bm + ar) * lda + k0 + ak];
    float4 bv = make_float4(0.f, 0.f, 0.f, 0.f);
    if (k0 + ak < K)
      bv = *(const float4*)&W[(size_t)(nw + ar) * K + k0 + ak];
    __syncthreads();
    As[ak + 0][ar] = av.x; As[ak + 1][ar] = av.y;
    As[ak + 2][ar] = av.z; As[ak + 3][ar] = av.w;
    Bs[ak + 0][ar] = bv.x; Bs[ak + 1][ar] = bv.y;
    Bs[ak + 2][ar] = bv.z; Bs[ak + 3][ar] = bv.w;
    __syncthreads();
#pragma unroll
    for (int kk = 0; kk < BK; ++kk) {
      float4 a4 = *(const float4*)&As[kk][ty * 4];
      float4 b4 = *(const float4*)&Bs[kk][tx * 4];
      float a_[4] = {a4.x, a4.y, a4.z, a4.w};
      float b_[4] = {b4.x, b4.y, b4.z, b4.w};
#pragma unroll
      for (int i = 0; i < 4; ++i)
#pragma unroll
        for (int j = 0; j < 4; ++j)
          acc[i][j] = fmaf(a_[i], b_[j], acc[i][j]);
    }
  }
  const float4 bias4 = *(const float4*)&bs[nw + tx * 4];
#pragma unroll
  for (int i = 0; i < 4; ++i) {
    float4 o;
    o.x = acc[i][0] + bias4.x;
    o.y = acc[i][1] + bias4.y;
    o.z = acc[i][2] + bias4.z;
    o.w = acc[i][3] + bias4.w;
    *(float4*)&out[(size_t)(bm + ty * 4 + i) * XPD + n0 + tx * 4] = o;
  }
}

// Stash one packed bf16x8 fragment (4 dwords) into hard-named AGPRs.
#define STASH4(A0, A1, A2, A3, V)                                  \
  asm volatile("v_accvgpr_write_b32 " A0 ", %0\n\t"                \
               "v_accvgpr_write_b32 " A1 ", %1\n\t"                \
               "v_accvgpr_write_b32 " A2 ", %2\n\t"                \
               "v_accvgpr_write_b32 " A3 ", %3"                    \
               :: "v"(V[0]), "v"(V[1]), "v"(V[2]), "v"(V[3])       \
               : A0, A1, A2, A3, "memory")

// Load 8 fp32 weights, split into bf16 hi/lo, pack, stash hi+lo fragments.
// Wave covers hidden units [wv*16, wv*16+16); weight row = TN*128+wtile+ln15.
#define FRAG(TN, KC, H0,H1,H2,H3, L0,L1,L2,L3)                     \
  do {                                                             \
    const float* wp_ = whh + (size_t)((TN)*128 + wtile + ln15)*HID \
                       + (KC)*32 + kg8;                            \
    float4 f0_ = *(const float4*)wp_;                              \
    float4 f1_ = *(const float4*)(wp_ + 4);                        \
    ux4 H_, L_;                                                    \
    H_[0] = pack2(f0_.x, f0_.y);  H_[1] = pack2(f0_.z, f0_.w);     \
    H_[2] = pack2(f1_.x, f1_.y);  H_[3] = pack2(f1_.z, f1_.w);     \
    L_[0] = pack2(lof(f0_.x), lof(f0_.y));                         \
    L_[1] = pack2(lof(f0_.z), lof(f0_.w));                         \
    L_[2] = pack2(lof(f1_.x), lof(f1_.y));                         \
    L_[3] = pack2(lof(f1_.z), lof(f1_.w));                         \
    STASH4(H0, H1, H2, H3, H_);                                    \
    STASH4(L0, L1, L2, L3, L_);                                    \
  } while (0)

// all AGPRs the kernel manages by hand: weights a0-127, accs a128-159, zero a160-163
#define ACLOB                                                       \
  "a0","a1","a2","a3","a4","a5","a6","a7","a8","a9","a10","a11",    \
  "a12","a13","a14","a15","a16","a17","a18","a19","a20","a21",      \
  "a22","a23","a24","a25","a26","a27","a28","a29","a30","a31",      \
  "a32","a33","a34","a35","a36","a37","a38","a39","a40","a41",      \
  "a42","a43","a44","a45","a46","a47","a48","a49","a50","a51",      \
  "a52","a53","a54","a55","a56","a57","a58","a59","a60","a61",      \
  "a62","a63","a64","a65","a66","a67","a68","a69","a70","a71",      \
  "a72","a73","a74","a75","a76","a77","a78","a79","a80","a81",      \
  "a82","a83","a84","a85","a86","a87","a88","a89","a90","a91",      \
  "a92","a93","a94","a95","a96","a97","a98","a99","a100","a101",    \
  "a102","a103","a104","a105","a106","a107","a108","a109","a110",   \
  "a111","a112","a113","a114","a115","a116","a117","a118","a119",   \
  "a120","a121","a122","a123","a124","a125","a126","a127",          \
  "a128","a129","a130","a131","a132","a133","a134","a135",          \
  "a136","a137","a138","a139","a140","a141","a142","a143",          \
  "a144","a145","a146","a147","a148","a149","a150","a151",          \
  "a152","a153","a154","a155","a156","a157","a158","a159",          \
  "a160","a161","a162","a163"

// ---------------- kernel 4: MFMA persistent LSTM, fused per-step asm block
// 512 thr = 8 waves per direction; wave w owns all four gates of units
// [16w,16w+16). Weights (bf16 hi/lo) in AGPRs a0-a127; per-step accumulators
// in AGPRs a128-a159 with zero-quad a160-163 as srcC of each chain's first
// MFMA (kills acc-init movs); ONE asm block per step (kills the per-boundary
// register shuffling that made round 10 issue ~325 VALU instr/wave/step).
__global__ __launch_bounds__(512) void k_lstm(
    const float* __restrict__ xp,     // [T][1024] (f cols 0:512, b cols 512:1024)
    const float* __restrict__ whh_f,  // [512][128]
    const float* __restrict__ whh_b,
    float* __restrict__ hout) {       // [T][256] (f cols 0:128, b cols 128:256)
  const int dir = blockIdx.x;
  const int tid = threadIdx.x;   // 0..511
  const int wv  = tid >> 6;      // wave 0..7
  const int ln  = tid & 63;      // lane
  const int ln15 = ln & 15;      // spatial index within fragment
  const int kg8  = (ln >> 4) * 8;  // k-subgroup offset
  const int wtile = wv * 16;     // this wave's hidden-unit base
  const float* __restrict__ whh = dir ? whh_b : whh_f;
  const int xofs = dir * GATES;
  const int hofs = dir * HID;

  __shared__ __align__(16) float lx[2 * 8 * GATES];        // xp ring, 32 KB
  __shared__ __align__(16) unsigned short hbf[2][2][136];  // h bf16 hi/lo, dbuf

  // ---- prologue: convert + stash weight fragments into AGPRs
  FRAG(0, 0, "a0","a1","a2","a3",     "a64","a65","a66","a67");
  FRAG(0, 1, "a4","a5","a6","a7",     "a68","a69","a70","a71");
  FRAG(0, 2, "a8","a9","a10","a11",   "a72","a73","a74","a75");
  FRAG(0, 3, "a12","a13","a14","a15", "a76","a77","a78","a79");
  FRAG(1, 0, "a16","a17","a18","a19", "a80","a81","a82","a83");
  FRAG(1, 1, "a20","a21","a22","a23", "a84","a85","a86","a87");
  FRAG(1, 2, "a24","a25","a26","a27", "a88","a89","a90","a91");
  FRAG(1, 3, "a28","a29","a30","a31", "a92","a93","a94","a95");
  FRAG(2, 0, "a32","a33","a34","a35", "a96","a97","a98","a99");
  FRAG(2, 1, "a36","a37","a38","a39", "a100","a101","a102","a103");
  FRAG(2, 2, "a40","a41","a42","a43", "a104","a105","a106","a107");
  FRAG(2, 3, "a44","a45","a46","a47", "a108","a109","a110","a111");
  FRAG(3, 0, "a48","a49","a50","a51", "a112","a113","a114","a115");
  FRAG(3, 1, "a52","a53","a54","a55", "a116","a117","a118","a119");
  FRAG(3, 2, "a56","a57","a58","a59", "a120","a121","a122","a123");
  FRAG(3, 3, "a60","a61","a62","a63", "a124","a125","a126","a127");
  {  // zero quad for srcC of first MFMA per chain
    float z = 0.0f;
    asm volatile("v_accvgpr_write_b32 a160, %0\n\t"
                 "v_accvgpr_write_b32 a161, %0\n\t"
                 "v_accvgpr_write_b32 a162, %0\n\t"
                 "v_accvgpr_write_b32 a163, %0"
                 :: "v"(z) : "a160","a161","a162","a163");
  }

  // ---- stage xp group 0 into ring buffer 0; thread covers 8 floats
  const int xu = tid >> 6;          // step-in-group 0..7
  const int xc = (tid & 63) * 8;    // col 0..504
  {
    const int tt = dir ? (T_SEQ - 1 - xu) : xu;
    const float* gp = xp + (size_t)tt * XPD + xofs + xc;
    *(fx4*)&lx[tid * 8]     = *(const fx4*)gp;
    *(fx4*)&lx[tid * 8 + 4] = *(const fx4*)(gp + 4);
  }
  float c = 0.0f;
  if (tid < HID) {
    hbf[0][0][tid] = 0; hbf[0][1][tid] = 0;
  }
  // per-thread incremental hout pointer (unit wtile+ln15)
  float* hp = hout + (size_t)(dir ? (T_SEQ - 1) : 0) * 256 + hofs + wtile + ln15;
  const ptrdiff_t hstep = dir ? -256 : 256;

  __syncthreads();

  int buf = 0;
  for (int t0 = 0; t0 < T_SEQ; t0 += 8) {
    // issue next group's xp loads via raw asm (drained at u==7 vmcnt(0))
    const int tb = (t0 + 8 < T_SEQ) ? t0 + 8 : 0;
    fx4 xr0, xr1;
    {
      const int tg = tb + xu;
      const int tt = dir ? (T_SEQ - 1 - tg) : tg;
      const float* gp = xp + (size_t)tt * XPD + xofs + xc;
      asm volatile("global_load_dwordx4 %0, %2, off\n\t"
                   "global_load_dwordx4 %1, %2, off offset:16"
                   : "=&v"(xr0), "=&v"(xr1) : "v"(gp));
    }
    const float* lxb = lx + buf * (8 * GATES);
#pragma unroll
    for (int u = 0; u < 8; ++u) {
      const int p = u & 1;  // t0 even -> parity compile-time per u
      // xp addends for this step
      const float* xrow = lxb + u * GATES + wtile + ln15;
      float x_i = xrow[0];
      float x_f = xrow[128];
      float x_g = xrow[256];
      float x_o = xrow[384];
      // A-fragments from hbf[p]: row0 lanes h_hi, row1 lanes h_lo
      const unsigned short* ap =
          (ln15 == 1 ? &hbf[p][1][0] : &hbf[p][0][0]) + kg8;
      ux4 av0 = *(const ux4*)(ap);
      ux4 av1 = *(const ux4*)(ap + 32);
      ux4 av2 = *(const ux4*)(ap + 64);
      ux4 av3 = *(const ux4*)(ap + 96);
      // fused matrix phase: 32 MFMA + drain nops + 16 accvgpr reads.
      // chains (D): hi i/f/g/o = a[128:131..140:143], lo = a[144:147..156:159]
      float ih0, ih1, il0, il1, fh0, fh1, fl0, fl1;
      float gh0, gh1, gl0, gl1, oh0, oh1, ol0, ol1;
      asm volatile(
        // kc0: srcC = zero quad
        "v_mfma_f32_16x16x32_bf16 a[128:131], %16, a[0:3],     a[160:163]\n\t"
        "v_mfma_f32_16x16x32_bf16 a[132:135], %16, a[16:19],   a[160:163]\n\t"
        "v_mfma_f32_16x16x32_bf16 a[136:139], %16, a[32:35],   a[160:163]\n\t"
        "v_mfma_f32_16x16x32_bf16 a[140:143], %16, a[48:51],   a[160:163]\n\t"
        "v_mfma_f32_16x16x32_bf16 a[144:147], %16, a[64:67],   a[160:163]\n\t"
        "v_mfma_f32_16x16x32_bf16 a[148:151], %16, a[80:83],   a[160:163]\n\t"
        "v_mfma_f32_16x16x32_bf16 a[152:155], %16, a[96:99],   a[160:163]\n\t"
        "v_mfma_f32_16x16x32_bf16 a[156:159], %16, a[112:115], a[160:163]\n\t"
        // kc1
        "v_mfma_f32_16x16x32_bf16 a[128:131], %17, a[4:7],     a[128:131]\n\t"
        "v_mfma_f32_16x16x32_bf16 a[132:135], %17, a[20:23],   a[132:135]\n\t"
        "v_mfma_f32_16x16x32_bf16 a[136:139], %17, a[36:39],   a[136:139]\n\t"
        "v_mfma_f32_16x16x32_bf16 a[140:143], %17, a[52:55],   a[140:143]\n\t"
        "v_mfma_f32_16x16x32_bf16 a[144:147], %17, a[68:71],   a[144:147]\n\t"
        "v_mfma_f32_16x16x32_bf16 a[148:151], %17, a[84:87],   a[148:151]\n\t"
        "v_mfma_f32_16x16x32_bf16 a[152:155], %17, a[100:103], a[152:155]\n\t"
        "v_mfma_f32_16x16x32_bf16 a[156:159], %17, a[116:119], a[156:159]\n\t"
        // kc2
        "v_mfma_f32_16x16x32_bf16 a[128:131], %18, a[8:11],    a[128:131]\n\t"
        "v_mfma_f32_16x16x32_bf16 a[132:135], %18, a[24:27],   a[132:135]\n\t"
        "v_mfma_f32_16x16x32_bf16 a[136:139], %18, a[40:43],   a[136:139]\n\t"
        "v_mfma_f32_16x16x32_bf16 a[140:143], %18, a[56:59],   a[140:143]\n\t"
        "v_mfma_f32_16x16x32_bf16 a[144:147], %18, a[72:75],   a[144:147]\n\t"
        "v_mfma_f32_16x16x32_bf16 a[148:151], %18, a[88:91],   a[148:151]\n\t"
        "v_mfma_f32_16x16x32_bf16 a[152:155], %18, a[104:107], a[152:155]\n\t"
        "v_mfma_f32_16x16x32_bf16 a[156:159], %18, a[120:123], a[156:159]\n\t"
        // kc3
        "v_mfma_f32_16x16x32_bf16 a[128:131], %19, a[12:15],   a[128:131]\n\t"
        "v_mfma_f32_16x16x32_bf16 a[132:135], %19, a[28:31],   a[132:135]\n\t"
        "v_mfma_f32_16x16x32_bf16 a[136:139], %19, a[44:47],   a[136:139]\n\t"
        "v_mfma_f32_16x16x32_bf16 a[140:143], %19, a[60:63],   a[140:143]\n\t"
        "v_mfma_f32_16x16x32_bf16 a[144:147], %19, a[76:79],   a[144:147]\n\t"
        "v_mfma_f32_16x16x32_bf16 a[148:151], %19, a[92:95],   a[148:151]\n\t"
        "v_mfma_f32_16x16x32_bf16 a[152:155], %19, a[108:111], a[152:155]\n\t"
        "v_mfma_f32_16x16x32_bf16 a[156:159], %19, a[124:127], a[156:159]\n\t"
        "s_nop 7\n\t"
        "s_nop 7\n\t"
        "v_accvgpr_read_b32 %0,  a128\n\t"
        "v_accvgpr_read_b32 %1,  a129\n\t"
        "v_accvgpr_read_b32 %2,  a144\n\t"
        "v_accvgpr_read_b32 %3,  a145\n\t"
        "v_accvgpr_read_b32 %4,  a132\n\t"
        "v_accvgpr_read_b32 %5,  a133\n\t"
        "v_accvgpr_read_b32 %6,  a148\n\t"
        "v_accvgpr_read_b32 %7,  a149\n\t"
        "v_accvgpr_read_b32 %8,  a136\n\t"
        "v_accvgpr_read_b32 %9,  a137\n\t"
        "v_accvgpr_read_b32 %10, a152\n\t"
        "v_accvgpr_read_b32 %11, a153\n\t"
        "v_accvgpr_read_b32 %12, a140\n\t"
        "v_accvgpr_read_b32 %13, a141\n\t"
        "v_accvgpr_read_b32 %14, a156\n\t"
        "v_accvgpr_read_b32 %15, a157"
        : "=v"(ih0), "=v"(ih1), "=v"(il0), "=v"(il1),
          "=v"(fh0), "=v"(fh1), "=v"(fl0), "=v"(fl1),
          "=v"(gh0), "=v"(gh1), "=v"(gl0), "=v"(gl1),
          "=v"(oh0), "=v"(oh1), "=v"(ol0), "=v"(ol1)
        : "v"(av0), "v"(av1), "v"(av2), "v"(av3)
        : ACLOB);
      // gate = hi(row0+row1) + lo(row0+row1) + xp ; activation ; update
      float i_g = sigm(((ih0 + ih1) + (il0 + il1)) + x_i);
      float f_g = sigm(((fh0 + fh1) + (fl0 + fl1)) + x_f);
      float g_g = tanh_f(((gh0 + gh1) + (gl0 + gl1)) + x_g);
      float o_g = sigm(((oh0 + oh1) + (ol0 + ol1)) + x_o);
      c = f_g * c + i_g * g_g;
      float h = o_g * tanh_f(c);
      if (ln < 16) {
        unsigned int hh = f2bf1(h);
        float hr = h - bf2f(hh);
        hbf[p ^ 1][0][wtile + ln15] = (unsigned short)hh;
        hbf[p ^ 1][1][wtile + ln15] = (unsigned short)f2bf1(hr);
        *hp = h;  // fire-and-forget global store
      }
      hp += hstep;
      if (u == 7) {
        asm volatile("s_waitcnt vmcnt(0)" ::: "memory");
        *(fx4*)&lx[(buf ^ 1) * (8 * GATES) + tid * 8]     = xr0;
        *(fx4*)&lx[(buf ^ 1) * (8 * GATES) + tid * 8 + 4] = xr1;
      }
      asm volatile("s_waitcnt lgkmcnt(0)" ::: "memory");
      __builtin_amdgcn_s_barrier();
    }
    buf ^= 1;
  }
}

// ---------------- kernel 5: tag_space = h2 @ W_out^T + b_out
__global__ void k_out(const float* __restrict__ h2,
                      const float* __restrict__ Wout,
                      const float* __restrict__ bout,
                      float* __restrict__ out) {
  __shared__ __align__(16) float hrow[256];
  const int t = blockIdx.x;
  const int tid = threadIdx.x;  // 64
  *(float4*)&hrow[tid * 4] = *(const float4*)&h2[(size_t)t * 256 + tid * 4];
  __syncthreads();
  if (tid < TAGS) {
    float acc = bout[tid];
    const float* w = &Wout[(size_t)tid * 256];
#pragma unroll 8
    for (int k = 0; k < 256; k += 4) {
      float4 wv = *(const float4*)&w[k];
      acc += hrow[k] * wv.x + hrow[k + 1] * wv.y + hrow[k + 2] * wv.z +
             hrow[k + 3] * wv.w;
    }
    out[(size_t)t * TAGS + tid] = acc;
  }
}

extern "C" void kernel_launch(void* const* d_in, const int* in_sizes, int n_in,
                              void* d_out, int out_size, void* d_ws, size_t ws_size,
                              hipStream_t stream) {
  const int*   morp_ids = (const int*)d_in[0];
  const int*   seg      = (const int*)d_in[1];
  const int*   pred_idx = (const int*)d_in[2];
  const int*   dp_in    = (const int*)d_in[3];
  const float* feat     = (const float*)d_in[4];
  const float* W_wv     = (const float*)d_in[5];
  const float* dp_table = (const float*)d_in[6];
  const float* W_out    = (const float*)d_in[7];
  const float* b_out    = (const float*)d_in[8];
  const float* w_ih_l0f = (const float*)d_in[9];
  const float* w_hh_l0f = (const float*)d_in[10];
  const float* b_l0f    = (const float*)d_in[11];
  const float* w_ih_l0b = (const float*)d_in[12];
  const float* w_hh_l0b = (const float*)d_in[13];
  const float* b_l0b    = (const float*)d_in[14];
  const float* w_ih_l1f = (const float*)d_in[15];
  const float* w_hh_l1f = (const float*)d_in[16];
  const float* b_l1f    = (const float*)d_in[17];
  const float* w_ih_l1b = (const float*)d_in[18];
  const float* w_hh_l1b = (const float*)d_in[19];
  const float* b_l1b    = (const float*)d_in[20];
  float* out = (float*)d_out;

  float* ws  = (float*)d_ws;
  float* inp = ws;                      // 2048*304
  float* xp  = inp + 2048 * LDA0;       // 2048*1024 (reused for both layers)
  float* h1  = xp + 2048 * XPD;         // 2048*256
  float* h2  = h1 + 2048 * 256;         // 2048*256

  k_toksum<<<2048, 128, 0, stream>>>(W_wv, morp_ids, seg, inp);
  k_fill<<<2048, 256, 0, stream>>>(dp_table, dp_in, feat, pred_idx, inp);

  dim3 gg(32, 16);
  k_gemm<<<gg, 256, 0, stream>>>(inp, LDA0, 300, w_ih_l0f, w_ih_l0b, b_l0f, b_l0b, xp);
  k_lstm<<<2, 512, 0, stream>>>(xp, w_hh_l0f, w_hh_l0b, h1);
  k_gemm<<<gg, 256, 0, stream>>>(h1, 256, 256, w_ih_l1f, w_ih_l1b, b_l1f, b_l1b, xp);
  k_lstm<<<2, 512, 0, stream>>>(xp, w_hh_l1f, w_hh_l1b, h2);
  k_out<<<2048, 64, 0, stream>>>(h2, W_out, b_out, out);
}